// Round 2
// baseline (356.175 us; speedup 1.0000x reference)
//
#include <hip/hip_runtime.h>
#include <hip/hip_bf16.h>

// ---------------------------------------------------------------------------
// GCN forward: out = A_hat @ ( (relu(A_hat @ (X@W1))) @ W2 )
// A_hat = D^-1/2 (A) D^-1/2, edges given as (row, col) pairs incl. self loops.
//
// R2: internal tensors bf16, GEMMs on MFMA 16x16x32_bf16, SpMM gathers bf16.
// R3: csr_w eliminated (w separable) — GEMM epilogues pre-scale rows by dinv.
// R4: CSR build via 2-level counting sort (all atomics in LDS).
// R5: deg from binP histogram (no global atomics).
// R6: SpMM restructured: 16 lanes/row, 4 rows/wave, dwordx4 gathers.
// R7: SpMM: float2 packed accumulation (v_pk_add_f32) + 4-deep edge unroll.
// R8: SpMM: block-cooperative LDS staging of csr_col (16 rows/block edge
//     range is contiguous). Kills the 16x-redundant per-lane cols loads
//     (-50% VMEM insts in hot loop) and removes the cols(L2)->gather(L3)
//     serial dependency from the critical path.
// ---------------------------------------------------------------------------

typedef __attribute__((ext_vector_type(8))) short short8;
typedef __attribute__((ext_vector_type(4))) float floatx4;
typedef __attribute__((ext_vector_type(2))) float floatx2;

static __device__ __forceinline__ ushort f32_to_bf16_bits(float f) {
    union { ushort u; __hip_bfloat16 b; } cv;
    cv.b = __float2bfloat16(f);
    return cv.u;
}
static __device__ __forceinline__ float bf16lo_to_f32(uint u) {
    return __uint_as_float(u << 16);
}
static __device__ __forceinline__ float bf16hi_to_f32(uint u) {
    return __uint_as_float(u & 0xffff0000u);
}
static __device__ __forceinline__ uint pack2bf(float a, float b) {
    return (uint)f32_to_bf16_bits(a) | ((uint)f32_to_bf16_bits(b) << 16);
}

#define CSR_EPB 8192
#define SPMM_CHUNK 2048   // LDS cols staging chunk (8 KB)

// ---- generic 3-phase device-wide exclusive scan (1024 elems per block) ----
__global__ __launch_bounds__(256) void scan_phase1_kernel(
    const int* __restrict__ in, int* __restrict__ out,
    int* __restrict__ block_total, int n) {
    __shared__ int tsum[256];
    int t = threadIdx.x;
    int base = blockIdx.x * 1024 + t * 4;
    int v0 = (base + 0 < n) ? in[base + 0] : 0;
    int v1 = (base + 1 < n) ? in[base + 1] : 0;
    int v2 = (base + 2 < n) ? in[base + 2] : 0;
    int v3 = (base + 3 < n) ? in[base + 3] : 0;
    tsum[t] = v0 + v1 + v2 + v3;
    __syncthreads();
    for (int off = 1; off < 256; off <<= 1) {
        int x = (t >= off) ? tsum[t - off] : 0;
        __syncthreads();
        tsum[t] += x;
        __syncthreads();
    }
    if (t == 255) block_total[blockIdx.x] = tsum[255];
    int run = (t == 0) ? 0 : tsum[t - 1];
    if (base + 0 < n) out[base + 0] = run; run += v0;
    if (base + 1 < n) out[base + 1] = run; run += v1;
    if (base + 2 < n) out[base + 2] = run; run += v2;
    if (base + 3 < n) out[base + 3] = run;
}

__global__ __launch_bounds__(256) void scan_phase2_kernel(
    const int* __restrict__ block_total, int* __restrict__ block_offset, int G) {
    __shared__ int s[256];
    int t = threadIdx.x;
    s[t] = (t < G) ? block_total[t] : 0;
    __syncthreads();
    for (int off = 1; off < 256; off <<= 1) {
        int x = (t >= off) ? s[t - off] : 0;
        __syncthreads();
        s[t] += x;
        __syncthreads();
    }
    if (t < G) block_offset[t] = (t == 0) ? 0 : s[t - 1];
    if (t == 0) block_offset[G] = s[255];
}

__global__ __launch_bounds__(256) void scan_phase3_kernel(
    int* __restrict__ arr, const int* __restrict__ block_offset, int n, int G) {
    int i = blockIdx.x * blockDim.x + threadIdx.x;
    if (i < n) arr[i] += block_offset[i >> 10];
    if (i == 0) arr[n] = block_offset[G];
}

// ---- CSR build: row-bucket counting sort (bucket = row>>9) ----------------

__global__ __launch_bounds__(256) void edge_hist_kernel(
    const int* __restrict__ keys, int* __restrict__ histG, int E, int nblk) {
    __shared__ int h[256];
    int t = threadIdx.x;
    h[t] = 0;
    __syncthreads();
    int base = blockIdx.x * CSR_EPB;
    int end = min(base + CSR_EPB, E);
    for (int i = base + t; i < end; i += 256)
        atomicAdd(&h[keys[i] >> 9], 1);
    __syncthreads();
    histG[t * nblk + blockIdx.x] = h[t];
}

// bin edges by row bucket -> packed (row&511)<<17 | col  (N < 2^17).
__global__ __launch_bounds__(256) void edge_bin_kernel(
    const int* __restrict__ rows, const int* __restrict__ colsIn,
    const int* __restrict__ offG, int* __restrict__ binP, int E, int nblk) {
    __shared__ int cur[256];
    int t = threadIdx.x;
    cur[t] = offG[t * nblk + blockIdx.x];
    __syncthreads();
    int base = blockIdx.x * CSR_EPB;
    int end = min(base + CSR_EPB, E);
    for (int i = base + t; i < end; i += 256) {
        int r = rows[i], c = colsIn[i];
        int p = atomicAdd(&cur[r >> 9], 1);
        binP[p] = ((r & 511) << 17) | c;
    }
}

// per-row degrees + dinv via per-bucket LDS histogram (no global atomics).
__global__ __launch_bounds__(256) void deg_dinv_from_bin_kernel(
    const int* __restrict__ binP, const int* __restrict__ offG,
    int* __restrict__ deg, float* __restrict__ dinv, int E, int nblk, int N) {
    __shared__ int cnt[512];
    int b = blockIdx.x;
    int rbase = b << 9;
    if (rbase >= N) return;
    int t = threadIdx.x;
    for (int i = t; i < 512; i += 256) cnt[i] = 0;
    __syncthreads();
    int bs = offG[b * nblk];
    int be = (b + 1 < 256) ? offG[(b + 1) * nblk] : E;
    for (int e = bs + t; e < be; e += 256)
        atomicAdd(&cnt[binP[e] >> 17], 1);
    __syncthreads();
    for (int i = t; i < 512; i += 256) {
        int r = rbase + i;
        if (r < N) {
            int d = cnt[i];
            deg[r] = d;
            dinv[r] = 1.0f / sqrtf(fmaxf((float)d, 1e-24f));
        }
    }
}

// one block per row bucket; LDS row cursors; scatter confined to this
// bucket's csr_col window (L2-resident).
__global__ __launch_bounds__(256) void edge_scatter_kernel(
    const int* __restrict__ binP, const int* __restrict__ offG,
    const int* __restrict__ row_ptr, int* __restrict__ csr_col,
    int E, int nblk, int N) {
    __shared__ int cur[512];
    int b = blockIdx.x;
    int rbase = b << 9;
    if (rbase >= N) return;
    int t = threadIdx.x;
    for (int i = t; i < 512; i += 256) {
        int r = rbase + i;
        cur[i] = (r < N) ? row_ptr[r] : 0;
    }
    __syncthreads();
    int bs = offG[b * nblk];
    int be = (b + 1 < 256) ? offG[(b + 1) * nblk] : E;
    for (int e = bs + t; e < be; e += 256) {
        int pk = binP[e];
        int rl = pk >> 17;
        int c = pk & 0x1ffff;
        int p = atomicAdd(&cur[rl], 1);
        csr_col[p] = c;
    }
}

// ---------------- fused weight cast + transpose (W1 and W2) ----------------
// W1t [128][256] <- W1 [256][128];  W2t [64][128] <- W2 [128][64].
__global__ void cast_weights_kernel(const float* __restrict__ W1, const float* __restrict__ W2,
                                    ushort* __restrict__ W1t, ushort* __restrict__ W2t) {
    int i = blockIdx.x * blockDim.x + threadIdx.x;
    if (i < 256 * 128) {
        int n = i >> 8, k = i & 255;           // W1t[n][k], K=256
        W1t[i] = f32_to_bf16_bits(W1[k * 128 + n]);
    } else {
        int j = i - 256 * 128;
        if (j < 128 * 64) {
            int n = j >> 7, k = j & 127;       // W2t[n][k], K=128
            W2t[j] = f32_to_bf16_bits(W2[k * 64 + n]);
        }
    }
}

// ---------------- MFMA GEMM -----------------------------------------------
// C[M,NCOLS](bf16) = dinv[row] * (A[M,KTOT] @ Bt^T); Bt is [NCOLS][KTOT] bf16.
// MFMA layouts (HW-verified per guide m89/m120):
//   a_frag lane l: A[m=l&15][k=(l>>4)*8+j]
//   b_frag lane l: B[k=(l>>4)*8+j][n=l&15]
//   d      lane l: D[row=(l>>4)*4+r][col=l&15]
template <int KTOT, int NCOLS, bool AF32>
__global__ __launch_bounds__(256) void gemm_mfma_kernel(
    const void* __restrict__ Aptr, const ushort* __restrict__ Bt,
    const float* __restrict__ dinv, ushort* __restrict__ Cbf, int M) {
    constexpr int KP = 128;
    constexpr int COLT = NCOLS / 16;
    __shared__ ushort Bs[NCOLS][KP + 8];
    int tid = threadIdx.x;
    int wave = tid >> 6, lane = tid & 63;
    int quad = lane >> 4, l16 = lane & 15;
    int row0 = blockIdx.x * 64;
    int rowA = row0 + wave * 16 + l16;
    int rowAc = min(rowA, M - 1);

    floatx4 acc[COLT];
#pragma unroll
    for (int t = 0; t < COLT; t++) acc[t] = (floatx4){0.f, 0.f, 0.f, 0.f};

    for (int kp = 0; kp < KTOT; kp += KP) {
        for (int u = tid; u < NCOLS * (KP / 8); u += 256) {
            int n = u / (KP / 8);
            int k8 = (u % (KP / 8)) * 8;
            *(short8*)&Bs[n][k8] = *(const short8*)(Bt + (size_t)n * KTOT + kp + k8);
        }
        __syncthreads();
#pragma unroll
        for (int kc = 0; kc < KP / 32; kc++) {
            int kk = kp + kc * 32 + quad * 8;
            short8 a;
            if (AF32) {
                const float* ap = (const float*)Aptr + (size_t)rowAc * KTOT + kk;
#pragma unroll
                for (int j = 0; j < 8; j++) a[j] = (short)f32_to_bf16_bits(ap[j]);
            } else {
                a = *(const short8*)((const ushort*)Aptr + (size_t)rowAc * KTOT + kk);
            }
#pragma unroll
            for (int t = 0; t < COLT; t++) {
                short8 b = *(const short8*)&Bs[t * 16 + l16][kc * 32 + quad * 8];
                acc[t] = __builtin_amdgcn_mfma_f32_16x16x32_bf16(a, b, acc[t], 0, 0, 0);
            }
        }
        __syncthreads();
    }

#pragma unroll
    for (int r = 0; r < 4; r++) {
        int row = row0 + wave * 16 + quad * 4 + r;
        if (row < M) {
            float dv = dinv[row];
#pragma unroll
            for (int t = 0; t < COLT; t++)
                Cbf[(size_t)row * NCOLS + t * 16 + l16] = f32_to_bf16_bits(dv * acc[t][r]);
        }
    }
}

// ---------------- SpMM: 16 lanes/row, 4 rows/wave, LDS-staged cols ---------
// Xin rows pre-scaled by dinv[col]; apply dinv[row] at the end.
// 16 rows/block -> block edge range [row_ptr[r0], row_ptr[r0+16]) is one
// contiguous slice of csr_col; staged to LDS in SPMM_CHUNK chunks.
// F=128: lane lg covers features lg*8..lg*8+7 (dwordx4 gather per edge).
__global__ __launch_bounds__(256) void spmm_f128_kernel(
    const int* __restrict__ row_ptr, const int* __restrict__ cols,
    const float* __restrict__ dinv, const ushort* __restrict__ Xin,
    ushort* __restrict__ Yout, int n) {
    __shared__ int cstage[SPMM_CHUNK];
    int r0 = blockIdx.x * 16;
    int tid = threadIdx.x;
    int wv = tid >> 6;
    int lane = tid & 63;
    int g = lane >> 4, lg = lane & 15;
    int row = r0 + wv * 4 + g;
    bool ok = row < n;
    int rc = ok ? row : (n - 1);
    int beg = row_ptr[rc];
    int end = ok ? row_ptr[rc + 1] : beg;
    int bbeg = row_ptr[r0];
    int bend = row_ptr[min(r0 + 16, n)];

    floatx2 acc2[4];
#pragma unroll
    for (int i = 0; i < 4; i++) acc2[i] = (floatx2){0.f, 0.f};

    const ushort* xb = Xin + lg * 8;

#define ACC_DW(U, D)                                            \
    {                                                            \
        floatx2 v_;                                              \
        v_.x = bf16lo_to_f32(U);                                 \
        v_.y = bf16hi_to_f32(U);                                 \
        acc2[D] += v_;                                           \
    }
#define ACC_U4(UU)                                               \
    ACC_DW(UU.x, 0) ACC_DW(UU.y, 1) ACC_DW(UU.z, 2) ACC_DW(UU.w, 3)

    for (int cb = bbeg; cb < bend; cb += SPMM_CHUNK) {
        int ce = min(cb + SPMM_CHUNK, bend);
        __syncthreads();
        for (int i = cb + tid; i < ce; i += 256)
            cstage[i - cb] = cols[i];
        __syncthreads();
        int s = max(beg, cb), t_ = min(end, ce);
        int e = s;
        for (; e + 4 <= t_; e += 4) {
            int c0 = cstage[e - cb], c1 = cstage[e + 1 - cb];
            int c2 = cstage[e + 2 - cb], c3 = cstage[e + 3 - cb];
            uint4 u0 = *(const uint4*)(xb + (size_t)c0 * 128);
            uint4 u1 = *(const uint4*)(xb + (size_t)c1 * 128);
            uint4 u2 = *(const uint4*)(xb + (size_t)c2 * 128);
            uint4 u3 = *(const uint4*)(xb + (size_t)c3 * 128);
            ACC_U4(u0) ACC_U4(u1) ACC_U4(u2) ACC_U4(u3)
        }
        for (; e < t_; e++) {
            int c = cstage[e - cb];
            uint4 u = *(const uint4*)(xb + (size_t)c * 128);
            ACC_U4(u)
        }
    }
#undef ACC_U4
#undef ACC_DW

    if (ok) {
        float dv = dinv[row];
        float a0 = fmaxf(dv * acc2[0].x, 0.f), a1 = fmaxf(dv * acc2[0].y, 0.f);
        float a2 = fmaxf(dv * acc2[1].x, 0.f), a3 = fmaxf(dv * acc2[1].y, 0.f);
        float a4 = fmaxf(dv * acc2[2].x, 0.f), a5 = fmaxf(dv * acc2[2].y, 0.f);
        float a6 = fmaxf(dv * acc2[3].x, 0.f), a7 = fmaxf(dv * acc2[3].y, 0.f);
        uint4 o;
        o.x = pack2bf(a0, a1);
        o.y = pack2bf(a2, a3);
        o.z = pack2bf(a4, a5);
        o.w = pack2bf(a6, a7);
        *(uint4*)(Yout + (size_t)row * 128 + lg * 8) = o;
    }
}

// F=64: lane lg covers features lg*4..lg*4+3 (dwordx2 gather), fp32 out.
__global__ __launch_bounds__(256) void spmm_f64_kernel(
    const int* __restrict__ row_ptr, const int* __restrict__ cols,
    const float* __restrict__ dinv, const ushort* __restrict__ Xin,
    float* __restrict__ Yout, int n) {
    __shared__ int cstage[SPMM_CHUNK];
    int r0 = blockIdx.x * 16;
    int tid = threadIdx.x;
    int wv = tid >> 6;
    int lane = tid & 63;
    int g = lane >> 4, lg = lane & 15;
    int row = r0 + wv * 4 + g;
    bool ok = row < n;
    int rc = ok ? row : (n - 1);
    int beg = row_ptr[rc];
    int end = ok ? row_ptr[rc + 1] : beg;
    int bbeg = row_ptr[r0];
    int bend = row_ptr[min(r0 + 16, n)];

    floatx2 acc2[2];
    acc2[0] = (floatx2){0.f, 0.f};
    acc2[1] = (floatx2){0.f, 0.f};

    const ushort* xb = Xin + lg * 4;

#define ACC_DW(U, D)                                            \
    {                                                            \
        floatx2 v_;                                              \
        v_.x = bf16lo_to_f32(U);                                 \
        v_.y = bf16hi_to_f32(U);                                 \
        acc2[D] += v_;                                           \
    }
#define ACC_U2(UU) ACC_DW(UU.x, 0) ACC_DW(UU.y, 1)

    for (int cb = bbeg; cb < bend; cb += SPMM_CHUNK) {
        int ce = min(cb + SPMM_CHUNK, bend);
        __syncthreads();
        for (int i = cb + tid; i < ce; i += 256)
            cstage[i - cb] = cols[i];
        __syncthreads();
        int s = max(beg, cb), t_ = min(end, ce);
        int e = s;
        for (; e + 4 <= t_; e += 4) {
            int c0 = cstage[e - cb], c1 = cstage[e + 1 - cb];
            int c2 = cstage[e + 2 - cb], c3 = cstage[e + 3 - cb];
            uint2 u0 = *(const uint2*)(xb + (size_t)c0 * 64);
            uint2 u1 = *(const uint2*)(xb + (size_t)c1 * 64);
            uint2 u2 = *(const uint2*)(xb + (size_t)c2 * 64);
            uint2 u3 = *(const uint2*)(xb + (size_t)c3 * 64);
            ACC_U2(u0) ACC_U2(u1) ACC_U2(u2) ACC_U2(u3)
        }
        for (; e < t_; e++) {
            int c = cstage[e - cb];
            uint2 u = *(const uint2*)(xb + (size_t)c * 64);
            ACC_U2(u)
        }
    }
#undef ACC_U2
#undef ACC_DW

    if (ok) {
        float dv = dinv[row];
        float4 o = make_float4(dv * acc2[0].x, dv * acc2[0].y,
                               dv * acc2[1].x, dv * acc2[1].y);
        *(float4*)(Yout + (size_t)row * 64 + lg * 4) = o;
    }
}

// ---------------- launch ----------------------------------------------------

extern "C" void kernel_launch(void* const* d_in, const int* in_sizes, int n_in,
                              void* d_out, int out_size, void* d_ws, size_t ws_size,
                              hipStream_t stream) {
    const float* X  = (const float*)d_in[0];
    const float* W1 = (const float*)d_in[1];
    const float* W2 = (const float*)d_in[2];
    const int* erow = (const int*)d_in[3];
    const int* ecol = (const int*)d_in[4];

    const int N = in_sizes[0] / 256;  // 100000 (< 2^17 for binP packing)
    const int E = in_sizes[3];        // 1700000
    const int G = (N + 1023) >> 10;   // row scan blocks (98 <= 256)

    const int nblk = (E + CSR_EPB - 1) / CSR_EPB;  // 208
    const int SL = 256 * nblk;                     // hist scan length
    const int GS = (SL + 1023) >> 10;              // 52 <= 256
    const int GMAX = (G > GS) ? G : GS;

    char* ws = (char*)d_ws;
    size_t off = 0;
    auto carve = [&](size_t bytes) -> char* {
        char* p = ws + off;
        off += (bytes + 255) & ~(size_t)255;
        return p;
    };
    int*    deg       = (int*)   carve((size_t)N * 4);
    float*  dinv      = (float*) carve((size_t)N * 4);
    int*    row_ptr   = (int*)   carve((size_t)(N + 1) * 4);
    int*    blk_total = (int*)   carve((size_t)GMAX * 4);
    int*    blk_off   = (int*)   carve((size_t)(GMAX + 1) * 4);
    int*    offG      = (int*)   carve((size_t)(SL + 1) * 4);
    // union: binP (E*4) dead before GEMM1 writes XW1 (N*128*2).
    size_t binP_bytes = (size_t)E * 4;
    size_t xw1_bytes  = (size_t)N * 128 * 2;
    char*  uni        = carve(binP_bytes > xw1_bytes ? binP_bytes : xw1_bytes);
    int*    binP      = (int*)uni;
    ushort* XW1       = (ushort*)uni;
    int*    csr_col   = (int*)   carve((size_t)E * 4);
    ushort* W1t       = (ushort*)carve((size_t)256 * 128 * 2);  // [128][256]
    ushort* W2t       = (ushort*)carve((size_t)128 * 64 * 2);   // [64][128]
    ushort* H         = (ushort*)carve((size_t)N * 128 * 2);
    ushort* HW2       = (ushort*)carve((size_t)N * 64 * 2);

    // --- CSR build: row-bucket counting sort ---
    edge_hist_kernel<<<nblk, 256, 0, stream>>>(erow, offG, E, nblk);
    scan_phase1_kernel<<<GS, 256, 0, stream>>>(offG, offG, blk_total, SL);
    scan_phase2_kernel<<<1, 256, 0, stream>>>(blk_total, blk_off, GS);
    scan_phase3_kernel<<<(SL + 255) / 256, 256, 0, stream>>>(offG, blk_off, SL, GS);
    edge_bin_kernel<<<nblk, 256, 0, stream>>>(erow, ecol, offG, binP, E, nblk);

    deg_dinv_from_bin_kernel<<<256, 256, 0, stream>>>(binP, offG, deg, dinv, E, nblk, N);
    scan_phase1_kernel<<<G, 256, 0, stream>>>(deg, row_ptr, blk_total, N);
    scan_phase2_kernel<<<1, 256, 0, stream>>>(blk_total, blk_off, G);
    scan_phase3_kernel<<<(N + 255) / 256, 256, 0, stream>>>(row_ptr, blk_off, N, G);

    edge_scatter_kernel<<<256, 256, 0, stream>>>(binP, offG, row_ptr, csr_col, E, nblk, N);

    // weights: cast + transpose to bf16 [n][k] (fused W1+W2)
    cast_weights_kernel<<<(256 * 128 + 128 * 64 + 255) / 256, 256, 0, stream>>>(W1, W2, W1t, W2t);

    // GEMM1: XW1(bf16) = dinv .* (X @ W1)   (overwrites binP — dead)
    gemm_mfma_kernel<256, 128, true><<<(N + 63) / 64, 256, 0, stream>>>(
        (const void*)X, W1t, dinv, XW1, N);

    // SpMM1: H(bf16) = relu(dinv .* sum gather XW1)
    spmm_f128_kernel<<<(N + 15) / 16, 256, 0, stream>>>(row_ptr, csr_col, dinv, XW1, H, N);

    // GEMM2: HW2(bf16) = dinv .* (H @ W2)
    gemm_mfma_kernel<128, 64, false><<<(N + 63) / 64, 256, 0, stream>>>(
        (const void*)H, W2t, dinv, HW2, N);

    // SpMM2: out(fp32) = dinv .* sum gather HW2
    spmm_f64_kernel<<<(N + 15) / 16, 256, 0, stream>>>(row_ptr, csr_col, dinv, HW2, (float*)d_out, N);
}

// Round 3
// 348.223 us; speedup vs baseline: 1.0228x; 1.0228x over previous
//
#include <hip/hip_runtime.h>
#include <hip/hip_bf16.h>

// ---------------------------------------------------------------------------
// GCN forward: out = A_hat @ ( (relu(A_hat @ (X@W1))) @ W2 )
// A_hat = D^-1/2 (A) D^-1/2, edges given as (row, col) pairs incl. self loops.
//
// R2-R8: bf16 internals, MFMA GEMMs, LDS counting-sort CSR, 16-lane/row SpMM
//        with dwordx4 gathers, packed f32x2 accumulation, LDS-staged cols.
// R9: (a) gemm2 fused INTO spmm_f128 (block's 16 H-rows -> LDS -> 4 MFMA/wave
//     -> write HW2 only). Kills gemm2 dispatch + H 25.6MB write + 25.6MB read.
//     (b) gather unroll 4->8 (spmm was 29% VALU / 0 MFMA / 3.5TB/s L2-miss
//     traffic => latency-bound; double MLP). cstage 2048->1024 (typ. block
//     has ~272 edges) -> fused LDS 25.7KB, 6 blocks/CU.
//     (c) chain-1 scan_phase3 folded into consumers (offG partial + blk_off1
//     at read); cast_weights folded into edge_hist grid. 15 -> 12 dispatches.
// ---------------------------------------------------------------------------

typedef __attribute__((ext_vector_type(8))) short short8;
typedef __attribute__((ext_vector_type(4))) float floatx4;
typedef __attribute__((ext_vector_type(2))) float floatx2;

static __device__ __forceinline__ ushort f32_to_bf16_bits(float f) {
    union { ushort u; __hip_bfloat16 b; } cv;
    cv.b = __float2bfloat16(f);
    return cv.u;
}
static __device__ __forceinline__ float bf16lo_to_f32(uint u) {
    return __uint_as_float(u << 16);
}
static __device__ __forceinline__ float bf16hi_to_f32(uint u) {
    return __uint_as_float(u & 0xffff0000u);
}
static __device__ __forceinline__ uint pack2bf(float a, float b) {
    return (uint)f32_to_bf16_bits(a) | ((uint)f32_to_bf16_bits(b) << 16);
}

#define CSR_EPB 8192
#define SPMM_CHUNK 1024   // LDS cols staging chunk (4 KB); loop handles overflow

// ---- generic 3-phase device-wide exclusive scan (1024 elems per block) ----
__global__ __launch_bounds__(256) void scan_phase1_kernel(
    const int* __restrict__ in, int* __restrict__ out,
    int* __restrict__ block_total, int n) {
    __shared__ int tsum[256];
    int t = threadIdx.x;
    int base = blockIdx.x * 1024 + t * 4;
    int v0 = (base + 0 < n) ? in[base + 0] : 0;
    int v1 = (base + 1 < n) ? in[base + 1] : 0;
    int v2 = (base + 2 < n) ? in[base + 2] : 0;
    int v3 = (base + 3 < n) ? in[base + 3] : 0;
    tsum[t] = v0 + v1 + v2 + v3;
    __syncthreads();
    for (int off = 1; off < 256; off <<= 1) {
        int x = (t >= off) ? tsum[t - off] : 0;
        __syncthreads();
        tsum[t] += x;
        __syncthreads();
    }
    if (t == 255) block_total[blockIdx.x] = tsum[255];
    int run = (t == 0) ? 0 : tsum[t - 1];
    if (base + 0 < n) out[base + 0] = run; run += v0;
    if (base + 1 < n) out[base + 1] = run; run += v1;
    if (base + 2 < n) out[base + 2] = run; run += v2;
    if (base + 3 < n) out[base + 3] = run;
}

__global__ __launch_bounds__(256) void scan_phase2_kernel(
    const int* __restrict__ block_total, int* __restrict__ block_offset, int G) {
    __shared__ int s[256];
    int t = threadIdx.x;
    s[t] = (t < G) ? block_total[t] : 0;
    __syncthreads();
    for (int off = 1; off < 256; off <<= 1) {
        int x = (t >= off) ? s[t - off] : 0;
        __syncthreads();
        s[t] += x;
        __syncthreads();
    }
    if (t < G) block_offset[t] = (t == 0) ? 0 : s[t - 1];
    if (t == 0) block_offset[G] = s[255];
}

__global__ __launch_bounds__(256) void scan_phase3_kernel(
    int* __restrict__ arr, const int* __restrict__ block_offset, int n, int G) {
    int i = blockIdx.x * blockDim.x + threadIdx.x;
    if (i < n) arr[i] += block_offset[i >> 10];
    if (i == 0) arr[n] = block_offset[G];
}

// ---- CSR build: row-bucket counting sort (bucket = row>>9) ----------------
// Blocks [0,nblk): per-block 256-bucket histogram.
// Blocks [nblk,..): weight cast+transpose (W1t [128][256], W2t [64][128]).
__global__ __launch_bounds__(256) void edge_hist_cast_kernel(
    const int* __restrict__ keys, int* __restrict__ histG, int E, int nblk,
    const float* __restrict__ W1, const float* __restrict__ W2,
    ushort* __restrict__ W1t, ushort* __restrict__ W2t) {
    int b = blockIdx.x;
    if (b >= nblk) {
        int i = (b - nblk) * 256 + threadIdx.x;
        if (i < 256 * 128) {
            int n = i >> 8, k = i & 255;           // W1t[n][k], K=256
            W1t[i] = f32_to_bf16_bits(W1[k * 128 + n]);
        } else {
            int j = i - 256 * 128;
            if (j < 128 * 64) {
                int n = j >> 7, k = j & 127;       // W2t[n][k], K=128
                W2t[j] = f32_to_bf16_bits(W2[k * 64 + n]);
            }
        }
        return;
    }
    __shared__ int h[256];
    int t = threadIdx.x;
    h[t] = 0;
    __syncthreads();
    int base = b * CSR_EPB;
    int end = min(base + CSR_EPB, E);
    for (int i = base + t; i < end; i += 256)
        atomicAdd(&h[keys[i] >> 9], 1);
    __syncthreads();
    histG[t * nblk + b] = h[t];
}

// bin edges by row bucket -> packed (row&511)<<17 | col  (N < 2^17).
// offG is the PARTIAL scan; blk_off1[idx>>10] completes it (phase3 folded).
__global__ __launch_bounds__(256) void edge_bin_kernel(
    const int* __restrict__ rows, const int* __restrict__ colsIn,
    const int* __restrict__ offG, const int* __restrict__ blk_off1,
    int* __restrict__ binP, int E, int nblk) {
    __shared__ int cur[256];
    int t = threadIdx.x;
    int idx = t * nblk + blockIdx.x;
    cur[t] = offG[idx] + blk_off1[idx >> 10];
    __syncthreads();
    int base = blockIdx.x * CSR_EPB;
    int end = min(base + CSR_EPB, E);
    for (int i = base + t; i < end; i += 256) {
        int r = rows[i], c = colsIn[i];
        int p = atomicAdd(&cur[r >> 9], 1);
        binP[p] = ((r & 511) << 17) | c;
    }
}

// per-row degrees + dinv via per-bucket LDS histogram (no global atomics).
__global__ __launch_bounds__(256) void deg_dinv_from_bin_kernel(
    const int* __restrict__ binP, const int* __restrict__ offG,
    const int* __restrict__ blk_off1,
    int* __restrict__ deg, float* __restrict__ dinv, int E, int nblk, int N) {
    __shared__ int cnt[512];
    int b = blockIdx.x;
    int rbase = b << 9;
    if (rbase >= N) return;
    int t = threadIdx.x;
    for (int i = t; i < 512; i += 256) cnt[i] = 0;
    __syncthreads();
    int i0 = b * nblk;
    int bs = offG[i0] + blk_off1[i0 >> 10];
    int be = E;
    if (b + 1 < 256) {
        int i1 = (b + 1) * nblk;
        be = offG[i1] + blk_off1[i1 >> 10];
    }
    for (int e = bs + t; e < be; e += 256)
        atomicAdd(&cnt[binP[e] >> 17], 1);
    __syncthreads();
    for (int i = t; i < 512; i += 256) {
        int r = rbase + i;
        if (r < N) {
            int d = cnt[i];
            deg[r] = d;
            dinv[r] = 1.0f / sqrtf(fmaxf((float)d, 1e-24f));
        }
    }
}

// one block per row bucket; LDS row cursors; scatter confined to this
// bucket's csr_col window (L2-resident).
__global__ __launch_bounds__(256) void edge_scatter_kernel(
    const int* __restrict__ binP, const int* __restrict__ offG,
    const int* __restrict__ blk_off1,
    const int* __restrict__ row_ptr, int* __restrict__ csr_col,
    int E, int nblk, int N) {
    __shared__ int cur[512];
    int b = blockIdx.x;
    int rbase = b << 9;
    if (rbase >= N) return;
    int t = threadIdx.x;
    for (int i = t; i < 512; i += 256) {
        int r = rbase + i;
        cur[i] = (r < N) ? row_ptr[r] : 0;
    }
    __syncthreads();
    int i0 = b * nblk;
    int bs = offG[i0] + blk_off1[i0 >> 10];
    int be = E;
    if (b + 1 < 256) {
        int i1 = (b + 1) * nblk;
        be = offG[i1] + blk_off1[i1 >> 10];
    }
    for (int e = bs + t; e < be; e += 256) {
        int pk = binP[e];
        int rl = pk >> 17;
        int c = pk & 0x1ffff;
        int p = atomicAdd(&cur[rl], 1);
        csr_col[p] = c;
    }
}

// ---------------- MFMA GEMM (layer 1: X @ W1) ------------------------------
// C[M,NCOLS](bf16) = dinv[row] * (A[M,KTOT] @ Bt^T); Bt is [NCOLS][KTOT] bf16.
// MFMA layouts (HW-verified per guide m89/m120):
//   a_frag lane l: A[m=l&15][k=(l>>4)*8+j]
//   b_frag lane l: B[k=(l>>4)*8+j][n=l&15]
//   d      lane l: D[row=(l>>4)*4+r][col=l&15]
template <int KTOT, int NCOLS, bool AF32>
__global__ __launch_bounds__(256) void gemm_mfma_kernel(
    const void* __restrict__ Aptr, const ushort* __restrict__ Bt,
    const float* __restrict__ dinv, ushort* __restrict__ Cbf, int M) {
    constexpr int KP = 128;
    constexpr int COLT = NCOLS / 16;
    __shared__ ushort Bs[NCOLS][KP + 8];
    int tid = threadIdx.x;
    int wave = tid >> 6, lane = tid & 63;
    int quad = lane >> 4, l16 = lane & 15;
    int row0 = blockIdx.x * 64;
    int rowA = row0 + wave * 16 + l16;
    int rowAc = min(rowA, M - 1);

    floatx4 acc[COLT];
#pragma unroll
    for (int t = 0; t < COLT; t++) acc[t] = (floatx4){0.f, 0.f, 0.f, 0.f};

    for (int kp = 0; kp < KTOT; kp += KP) {
        for (int u = tid; u < NCOLS * (KP / 8); u += 256) {
            int n = u / (KP / 8);
            int k8 = (u % (KP / 8)) * 8;
            *(short8*)&Bs[n][k8] = *(const short8*)(Bt + (size_t)n * KTOT + kp + k8);
        }
        __syncthreads();
#pragma unroll
        for (int kc = 0; kc < KP / 32; kc++) {
            int kk = kp + kc * 32 + quad * 8;
            short8 a;
            if (AF32) {
                const float* ap = (const float*)Aptr + (size_t)rowAc * KTOT + kk;
#pragma unroll
                for (int j = 0; j < 8; j++) a[j] = (short)f32_to_bf16_bits(ap[j]);
            } else {
                a = *(const short8*)((const ushort*)Aptr + (size_t)rowAc * KTOT + kk);
            }
#pragma unroll
            for (int t = 0; t < COLT; t++) {
                short8 b = *(const short8*)&Bs[t * 16 + l16][kc * 32 + quad * 8];
                acc[t] = __builtin_amdgcn_mfma_f32_16x16x32_bf16(a, b, acc[t], 0, 0, 0);
            }
        }
        __syncthreads();
    }

#pragma unroll
    for (int r = 0; r < 4; r++) {
        int row = row0 + wave * 16 + quad * 4 + r;
        if (row < M) {
            float dv = dinv[row];
#pragma unroll
            for (int t = 0; t < COLT; t++)
                Cbf[(size_t)row * NCOLS + t * 16 + l16] = f32_to_bf16_bits(dv * acc[t][r]);
        }
    }
}

// ---------------- fused SpMM(F=128) + GEMM2 --------------------------------
// Per block: 16 rows. Phase A (SpMM): H-rows = relu(dinv .* gather-sum XW1),
// kept in registers, dropped to LDS as bf16. Phase B (GEMM2): 16x128 @
// 128x64 MFMA per block (wave wv handles cols wv*16..+15, 4 MFMA each),
// epilogue scales by dinv[row], writes HW2 only. H never touches global.
__global__ __launch_bounds__(256) void spmm_gemm2_kernel(
    const int* __restrict__ row_ptr, const int* __restrict__ cols,
    const float* __restrict__ dinv, const ushort* __restrict__ XW1,
    const ushort* __restrict__ W2t, ushort* __restrict__ HW2, int n) {
    __shared__ int cstage[SPMM_CHUNK];
    __shared__ ushort W2s[64][136];
    __shared__ ushort Hs[16][136];

    int tid = threadIdx.x;
    int wv = tid >> 6;
    int lane = tid & 63;
    int g = lane >> 4, lg = lane & 15;
    int r0 = blockIdx.x * 16;
    int row = r0 + wv * 4 + g;
    bool ok = row < n;
    int rc = ok ? row : (n - 1);
    int beg = row_ptr[rc];
    int end = ok ? row_ptr[rc + 1] : beg;
    int bbeg = row_ptr[r0];
    int bend = row_ptr[min(r0 + 16, n)];

    // stage W2t [64][128] -> W2s (read after the Hs barrier)
    for (int u = tid; u < 64 * 16; u += 256) {
        int nn = u >> 4, k8 = (u & 15) * 8;
        *(short8*)&W2s[nn][k8] = *(const short8*)(W2t + nn * 128 + k8);
    }

    floatx2 acc2[4];
#pragma unroll
    for (int i = 0; i < 4; i++) acc2[i] = (floatx2){0.f, 0.f};

    const ushort* xb = XW1 + lg * 8;

#define ACC_DW(U, D)                                            \
    {                                                            \
        floatx2 v_;                                              \
        v_.x = bf16lo_to_f32(U);                                 \
        v_.y = bf16hi_to_f32(U);                                 \
        acc2[D] += v_;                                           \
    }
#define ACC_U4(UU)                                               \
    ACC_DW(UU.x, 0) ACC_DW(UU.y, 1) ACC_DW(UU.z, 2) ACC_DW(UU.w, 3)

    for (int cb = bbeg; cb < bend; cb += SPMM_CHUNK) {
        int ce = min(cb + SPMM_CHUNK, bend);
        __syncthreads();
        for (int i = cb + tid; i < ce; i += 256)
            cstage[i - cb] = cols[i];
        __syncthreads();
        int s = max(beg, cb), t_ = min(end, ce);
        int e = s;
        for (; e + 8 <= t_; e += 8) {
            int c0 = cstage[e - cb], c1 = cstage[e + 1 - cb];
            int c2 = cstage[e + 2 - cb], c3 = cstage[e + 3 - cb];
            int c4 = cstage[e + 4 - cb], c5 = cstage[e + 5 - cb];
            int c6 = cstage[e + 6 - cb], c7 = cstage[e + 7 - cb];
            uint4 u0 = *(const uint4*)(xb + (size_t)c0 * 128);
            uint4 u1 = *(const uint4*)(xb + (size_t)c1 * 128);
            uint4 u2 = *(const uint4*)(xb + (size_t)c2 * 128);
            uint4 u3 = *(const uint4*)(xb + (size_t)c3 * 128);
            uint4 u4 = *(const uint4*)(xb + (size_t)c4 * 128);
            uint4 u5 = *(const uint4*)(xb + (size_t)c5 * 128);
            uint4 u6 = *(const uint4*)(xb + (size_t)c6 * 128);
            uint4 u7 = *(const uint4*)(xb + (size_t)c7 * 128);
            ACC_U4(u0) ACC_U4(u1) ACC_U4(u2) ACC_U4(u3)
            ACC_U4(u4) ACC_U4(u5) ACC_U4(u6) ACC_U4(u7)
        }
        for (; e + 4 <= t_; e += 4) {
            int c0 = cstage[e - cb], c1 = cstage[e + 1 - cb];
            int c2 = cstage[e + 2 - cb], c3 = cstage[e + 3 - cb];
            uint4 u0 = *(const uint4*)(xb + (size_t)c0 * 128);
            uint4 u1 = *(const uint4*)(xb + (size_t)c1 * 128);
            uint4 u2 = *(const uint4*)(xb + (size_t)c2 * 128);
            uint4 u3 = *(const uint4*)(xb + (size_t)c3 * 128);
            ACC_U4(u0) ACC_U4(u1) ACC_U4(u2) ACC_U4(u3)
        }
        for (; e < t_; e++) {
            int c = cstage[e - cb];
            uint4 u = *(const uint4*)(xb + (size_t)c * 128);
            ACC_U4(u)
        }
    }
#undef ACC_U4
#undef ACC_DW

    // H row -> LDS (zeros for padding rows)
    {
        float dv = ok ? dinv[row] : 0.f;
        float a0 = fmaxf(dv * acc2[0].x, 0.f), a1 = fmaxf(dv * acc2[0].y, 0.f);
        float a2 = fmaxf(dv * acc2[1].x, 0.f), a3 = fmaxf(dv * acc2[1].y, 0.f);
        float a4 = fmaxf(dv * acc2[2].x, 0.f), a5 = fmaxf(dv * acc2[2].y, 0.f);
        float a6 = fmaxf(dv * acc2[3].x, 0.f), a7 = fmaxf(dv * acc2[3].y, 0.f);
        uint4 o;
        o.x = pack2bf(a0, a1);
        o.y = pack2bf(a2, a3);
        o.z = pack2bf(a4, a5);
        o.w = pack2bf(a6, a7);
        *(uint4*)&Hs[wv * 4 + g][lg * 8] = o;
    }
    __syncthreads();

    // GEMM2: wave wv computes D[0:16][wv*16 : wv*16+16]
    int quad = g, l16 = lg;  // same decomposition
    floatx4 dacc = (floatx4){0.f, 0.f, 0.f, 0.f};
#pragma unroll
    for (int kc = 0; kc < 4; kc++) {
        short8 a = *(const short8*)&Hs[l16][kc * 32 + quad * 8];
        short8 b = *(const short8*)&W2s[wv * 16 + l16][kc * 32 + quad * 8];
        dacc = __builtin_amdgcn_mfma_f32_16x16x32_bf16(a, b, dacc, 0, 0, 0);
    }
#pragma unroll
    for (int r = 0; r < 4; r++) {
        int rowD = r0 + quad * 4 + r;
        if (rowD < n)
            HW2[(size_t)rowD * 64 + wv * 16 + l16] =
                f32_to_bf16_bits(dinv[rowD] * dacc[r]);
    }
}

// ---------------- SpMM F=64 (final layer), fp32 out ------------------------
__global__ __launch_bounds__(256) void spmm_f64_kernel(
    const int* __restrict__ row_ptr, const int* __restrict__ cols,
    const float* __restrict__ dinv, const ushort* __restrict__ Xin,
    float* __restrict__ Yout, int n) {
    __shared__ int cstage[SPMM_CHUNK];
    int r0 = blockIdx.x * 16;
    int tid = threadIdx.x;
    int wv = tid >> 6;
    int lane = tid & 63;
    int g = lane >> 4, lg = lane & 15;
    int row = r0 + wv * 4 + g;
    bool ok = row < n;
    int rc = ok ? row : (n - 1);
    int beg = row_ptr[rc];
    int end = ok ? row_ptr[rc + 1] : beg;
    int bbeg = row_ptr[r0];
    int bend = row_ptr[min(r0 + 16, n)];

    floatx2 acc2[2];
    acc2[0] = (floatx2){0.f, 0.f};
    acc2[1] = (floatx2){0.f, 0.f};

    const ushort* xb = Xin + lg * 4;

#define ACC_DW(U, D)                                            \
    {                                                            \
        floatx2 v_;                                              \
        v_.x = bf16lo_to_f32(U);                                 \
        v_.y = bf16hi_to_f32(U);                                 \
        acc2[D] += v_;                                           \
    }
#define ACC_U2(UU) ACC_DW(UU.x, 0) ACC_DW(UU.y, 1)

    for (int cb = bbeg; cb < bend; cb += SPMM_CHUNK) {
        int ce = min(cb + SPMM_CHUNK, bend);
        __syncthreads();
        for (int i = cb + tid; i < ce; i += 256)
            cstage[i - cb] = cols[i];
        __syncthreads();
        int s = max(beg, cb), t_ = min(end, ce);
        int e = s;
        for (; e + 8 <= t_; e += 8) {
            int c0 = cstage[e - cb], c1 = cstage[e + 1 - cb];
            int c2 = cstage[e + 2 - cb], c3 = cstage[e + 3 - cb];
            int c4 = cstage[e + 4 - cb], c5 = cstage[e + 5 - cb];
            int c6 = cstage[e + 6 - cb], c7 = cstage[e + 7 - cb];
            uint2 u0 = *(const uint2*)(xb + (size_t)c0 * 64);
            uint2 u1 = *(const uint2*)(xb + (size_t)c1 * 64);
            uint2 u2 = *(const uint2*)(xb + (size_t)c2 * 64);
            uint2 u3 = *(const uint2*)(xb + (size_t)c3 * 64);
            uint2 u4 = *(const uint2*)(xb + (size_t)c4 * 64);
            uint2 u5 = *(const uint2*)(xb + (size_t)c5 * 64);
            uint2 u6 = *(const uint2*)(xb + (size_t)c6 * 64);
            uint2 u7 = *(const uint2*)(xb + (size_t)c7 * 64);
            ACC_U2(u0) ACC_U2(u1) ACC_U2(u2) ACC_U2(u3)
            ACC_U2(u4) ACC_U2(u5) ACC_U2(u6) ACC_U2(u7)
        }
        for (; e + 4 <= t_; e += 4) {
            int c0 = cstage[e - cb], c1 = cstage[e + 1 - cb];
            int c2 = cstage[e + 2 - cb], c3 = cstage[e + 3 - cb];
            uint2 u0 = *(const uint2*)(xb + (size_t)c0 * 64);
            uint2 u1 = *(const uint2*)(xb + (size_t)c1 * 64);
            uint2 u2 = *(const uint2*)(xb + (size_t)c2 * 64);
            uint2 u3 = *(const uint2*)(xb + (size_t)c3 * 64);
            ACC_U2(u0) ACC_U2(u1) ACC_U2(u2) ACC_U2(u3)
        }
        for (; e < t_; e++) {
            int c = cstage[e - cb];
            uint2 u = *(const uint2*)(xb + (size_t)c * 64);
            ACC_U2(u)
        }
    }
#undef ACC_U2
#undef ACC_DW

    if (ok) {
        float dv = dinv[row];
        float4 o = make_float4(dv * acc2[0].x, dv * acc2[0].y,
                               dv * acc2[1].x, dv * acc2[1].y);
        *(float4*)(Yout + (size_t)row * 64 + lg * 4) = o;
    }
}

// ---------------- launch ----------------------------------------------------

extern "C" void kernel_launch(void* const* d_in, const int* in_sizes, int n_in,
                              void* d_out, int out_size, void* d_ws, size_t ws_size,
                              hipStream_t stream) {
    const float* X  = (const float*)d_in[0];
    const float* W1 = (const float*)d_in[1];
    const float* W2 = (const float*)d_in[2];
    const int* erow = (const int*)d_in[3];
    const int* ecol = (const int*)d_in[4];

    const int N = in_sizes[0] / 256;  // 100000 (< 2^17 for binP packing)
    const int E = in_sizes[3];        // 1700000
    const int G = (N + 1023) >> 10;   // row scan blocks (98 <= 256)

    const int nblk = (E + CSR_EPB - 1) / CSR_EPB;  // 208
    const int SL = 256 * nblk;                     // hist scan length
    const int GS = (SL + 1023) >> 10;              // 52 <= 256
    const int GMAX = (G > GS) ? G : GS;
    const int CAST_BLKS = (256 * 128 + 128 * 64 + 255) / 256;  // 160

    char* ws = (char*)d_ws;
    size_t off = 0;
    auto carve = [&](size_t bytes) -> char* {
        char* p = ws + off;
        off += (bytes + 255) & ~(size_t)255;
        return p;
    };
    int*    deg       = (int*)   carve((size_t)N * 4);
    float*  dinv      = (float*) carve((size_t)N * 4);
    int*    row_ptr   = (int*)   carve((size_t)(N + 1) * 4);
    int*    blk_total = (int*)   carve((size_t)GMAX * 4);
    int*    blk_off1  = (int*)   carve((size_t)(GMAX + 1) * 4);
    int*    blk_off2  = (int*)   carve((size_t)(GMAX + 1) * 4);
    int*    offG      = (int*)   carve((size_t)(SL + 1) * 4);
    // union: binP (E*4) dead before GEMM1 writes XW1 (N*128*2).
    size_t binP_bytes = (size_t)E * 4;
    size_t xw1_bytes  = (size_t)N * 128 * 2;
    char*  uni        = carve(binP_bytes > xw1_bytes ? binP_bytes : xw1_bytes);
    int*    binP      = (int*)uni;
    ushort* XW1       = (ushort*)uni;
    int*    csr_col   = (int*)   carve((size_t)E * 4);
    ushort* W1t       = (ushort*)carve((size_t)256 * 128 * 2);  // [128][256]
    ushort* W2t       = (ushort*)carve((size_t)128 * 64 * 2);   // [64][128]
    ushort* HW2       = (ushort*)carve((size_t)N * 64 * 2);

    // --- CSR build: row-bucket counting sort (+ weight cast piggy-backed) ---
    edge_hist_cast_kernel<<<nblk + CAST_BLKS, 256, 0, stream>>>(
        erow, offG, E, nblk, W1, W2, W1t, W2t);
    scan_phase1_kernel<<<GS, 256, 0, stream>>>(offG, offG, blk_total, SL);
    scan_phase2_kernel<<<1, 256, 0, stream>>>(blk_total, blk_off1, GS);
    // (chain-1 phase3 folded into consumers via blk_off1)
    edge_bin_kernel<<<nblk, 256, 0, stream>>>(erow, ecol, offG, blk_off1, binP, E, nblk);

    deg_dinv_from_bin_kernel<<<256, 256, 0, stream>>>(binP, offG, blk_off1, deg, dinv, E, nblk, N);
    scan_phase1_kernel<<<G, 256, 0, stream>>>(deg, row_ptr, blk_total, N);
    scan_phase2_kernel<<<1, 256, 0, stream>>>(blk_total, blk_off2, G);
    scan_phase3_kernel<<<(N + 255) / 256, 256, 0, stream>>>(row_ptr, blk_off2, N, G);

    edge_scatter_kernel<<<256, 256, 0, stream>>>(binP, offG, blk_off1, row_ptr, csr_col, E, nblk, N);

    // GEMM1: XW1(bf16) = dinv .* (X @ W1)   (overwrites binP — dead)
    gemm_mfma_kernel<256, 128, true><<<(N + 63) / 64, 256, 0, stream>>>(
        (const void*)X, W1t, dinv, XW1, N);

    // SpMM1 + GEMM2 fused: HW2(bf16) = dinv .* (relu(dinv .* gather XW1) @ W2)
    spmm_gemm2_kernel<<<(N + 15) / 16, 256, 0, stream>>>(
        row_ptr, csr_col, dinv, XW1, W2t, HW2, N);

    // SpMM2: out(fp32) = dinv .* sum gather HW2
    spmm_f64_kernel<<<(N + 15) / 16, 256, 0, stream>>>(row_ptr, csr_col, dinv, HW2, (float*)d_out, N);
}

// Round 7
// 347.472 us; speedup vs baseline: 1.0250x; 1.0022x over previous
//
#include <hip/hip_runtime.h>
#include <hip/hip_bf16.h>

// ---------------------------------------------------------------------------
// GCN forward: out = A_hat @ ( (relu(A_hat @ (X@W1))) @ W2 )
// A_hat = D^-1/2 (A) D^-1/2, edges given as (row, col) pairs incl. self loops.
//
// R2-R8: bf16 internals, MFMA GEMMs, LDS counting-sort CSR, 16-lane/row SpMM
//        with dwordx4 gathers, packed f32x2 accumulation, LDS-staged cols.
// R9: gemm2 fused into spmm (H stays on-chip); chain trimmed to 12 dispatches.
// R10: evidence: FETCH constant 186MB across structures; fill-BW tracks
//      occupancy (66%->3.55TB/s, 47%->3.10TB/s) => concurrency-bound miss
//      path. (a) W2s dropped from LDS (b-frags loaded from L2-hot W2t into
//      regs post-gather): fused LDS 26KB->8.4KB to restore occupancy.
//      (b) spmm_f64 -> 8 lanes/row x dwordx4 (half the VMEM insts/edge).
//      (c) gemm1 A-loads vectorized (2x float4, was 8x scalar dword).
// R11-R13: resubmits (rounds 4-6 failed on container acquisition, no data).
// ---------------------------------------------------------------------------

typedef __attribute__((ext_vector_type(8))) short short8;
typedef __attribute__((ext_vector_type(4))) float floatx4;
typedef __attribute__((ext_vector_type(2))) float floatx2;

static __device__ __forceinline__ ushort f32_to_bf16_bits(float f) {
    union { ushort u; __hip_bfloat16 b; } cv;
    cv.b = __float2bfloat16(f);
    return cv.u;
}
static __device__ __forceinline__ float bf16lo_to_f32(uint u) {
    return __uint_as_float(u << 16);
}
static __device__ __forceinline__ float bf16hi_to_f32(uint u) {
    return __uint_as_float(u & 0xffff0000u);
}
static __device__ __forceinline__ uint pack2bf(float a, float b) {
    return (uint)f32_to_bf16_bits(a) | ((uint)f32_to_bf16_bits(b) << 16);
}

#define CSR_EPB 8192
#define SPMM_CHUNK 1024   // LDS cols staging chunk (4 KB); loop handles overflow

// ---- generic 3-phase device-wide exclusive scan (1024 elems per block) ----
__global__ __launch_bounds__(256) void scan_phase1_kernel(
    const int* __restrict__ in, int* __restrict__ out,
    int* __restrict__ block_total, int n) {
    __shared__ int tsum[256];
    int t = threadIdx.x;
    int base = blockIdx.x * 1024 + t * 4;
    int v0 = (base + 0 < n) ? in[base + 0] : 0;
    int v1 = (base + 1 < n) ? in[base + 1] : 0;
    int v2 = (base + 2 < n) ? in[base + 2] : 0;
    int v3 = (base + 3 < n) ? in[base + 3] : 0;
    tsum[t] = v0 + v1 + v2 + v3;
    __syncthreads();
    for (int off = 1; off < 256; off <<= 1) {
        int x = (t >= off) ? tsum[t - off] : 0;
        __syncthreads();
        tsum[t] += x;
        __syncthreads();
    }
    if (t == 255) block_total[blockIdx.x] = tsum[255];
    int run = (t == 0) ? 0 : tsum[t - 1];
    if (base + 0 < n) out[base + 0] = run; run += v0;
    if (base + 1 < n) out[base + 1] = run; run += v1;
    if (base + 2 < n) out[base + 2] = run; run += v2;
    if (base + 3 < n) out[base + 3] = run;
}

__global__ __launch_bounds__(256) void scan_phase2_kernel(
    const int* __restrict__ block_total, int* __restrict__ block_offset, int G) {
    __shared__ int s[256];
    int t = threadIdx.x;
    s[t] = (t < G) ? block_total[t] : 0;
    __syncthreads();
    for (int off = 1; off < 256; off <<= 1) {
        int x = (t >= off) ? s[t - off] : 0;
        __syncthreads();
        s[t] += x;
        __syncthreads();
    }
    if (t < G) block_offset[t] = (t == 0) ? 0 : s[t - 1];
    if (t == 0) block_offset[G] = s[255];
}

__global__ __launch_bounds__(256) void scan_phase3_kernel(
    int* __restrict__ arr, const int* __restrict__ block_offset, int n, int G) {
    int i = blockIdx.x * blockDim.x + threadIdx.x;
    if (i < n) arr[i] += block_offset[i >> 10];
    if (i == 0) arr[n] = block_offset[G];
}

// ---- CSR build: row-bucket counting sort (bucket = row>>9) ----------------
// Blocks [0,nblk): per-block 256-bucket histogram.
// Blocks [nblk,..): weight cast+transpose (W1t [128][256], W2t [64][128]).
__global__ __launch_bounds__(256) void edge_hist_cast_kernel(
    const int* __restrict__ keys, int* __restrict__ histG, int E, int nblk,
    const float* __restrict__ W1, const float* __restrict__ W2,
    ushort* __restrict__ W1t, ushort* __restrict__ W2t) {
    int b = blockIdx.x;
    if (b >= nblk) {
        int i = (b - nblk) * 256 + threadIdx.x;
        if (i < 256 * 128) {
            int n = i >> 8, k = i & 255;           // W1t[n][k], K=256
            W1t[i] = f32_to_bf16_bits(W1[k * 128 + n]);
        } else {
            int j = i - 256 * 128;
            if (j < 128 * 64) {
                int n = j >> 7, k = j & 127;       // W2t[n][k], K=128
                W2t[j] = f32_to_bf16_bits(W2[k * 64 + n]);
            }
        }
        return;
    }
    __shared__ int h[256];
    int t = threadIdx.x;
    h[t] = 0;
    __syncthreads();
    int base = b * CSR_EPB;
    int end = min(base + CSR_EPB, E);
    for (int i = base + t; i < end; i += 256)
        atomicAdd(&h[keys[i] >> 9], 1);
    __syncthreads();
    histG[t * nblk + b] = h[t];
}

// bin edges by row bucket -> packed (row&511)<<17 | col  (N < 2^17).
// offG is the PARTIAL scan; blk_off1[idx>>10] completes it (phase3 folded).
__global__ __launch_bounds__(256) void edge_bin_kernel(
    const int* __restrict__ rows, const int* __restrict__ colsIn,
    const int* __restrict__ offG, const int* __restrict__ blk_off1,
    int* __restrict__ binP, int E, int nblk) {
    __shared__ int cur[256];
    int t = threadIdx.x;
    int idx = t * nblk + blockIdx.x;
    cur[t] = offG[idx] + blk_off1[idx >> 10];
    __syncthreads();
    int base = blockIdx.x * CSR_EPB;
    int end = min(base + CSR_EPB, E);
    for (int i = base + t; i < end; i += 256) {
        int r = rows[i], c = colsIn[i];
        int p = atomicAdd(&cur[r >> 9], 1);
        binP[p] = ((r & 511) << 17) | c;
    }
}

// per-row degrees + dinv via per-bucket LDS histogram (no global atomics).
__global__ __launch_bounds__(256) void deg_dinv_from_bin_kernel(
    const int* __restrict__ binP, const int* __restrict__ offG,
    const int* __restrict__ blk_off1,
    int* __restrict__ deg, float* __restrict__ dinv, int E, int nblk, int N) {
    __shared__ int cnt[512];
    int b = blockIdx.x;
    int rbase = b << 9;
    if (rbase >= N) return;
    int t = threadIdx.x;
    for (int i = t; i < 512; i += 256) cnt[i] = 0;
    __syncthreads();
    int i0 = b * nblk;
    int bs = offG[i0] + blk_off1[i0 >> 10];
    int be = E;
    if (b + 1 < 256) {
        int i1 = (b + 1) * nblk;
        be = offG[i1] + blk_off1[i1 >> 10];
    }
    for (int e = bs + t; e < be; e += 256)
        atomicAdd(&cnt[binP[e] >> 17], 1);
    __syncthreads();
    for (int i = t; i < 512; i += 256) {
        int r = rbase + i;
        if (r < N) {
            int d = cnt[i];
            deg[r] = d;
            dinv[r] = 1.0f / sqrtf(fmaxf((float)d, 1e-24f));
        }
    }
}

// one block per row bucket; LDS row cursors; scatter confined to this
// bucket's csr_col window (L2-resident).
__global__ __launch_bounds__(256) void edge_scatter_kernel(
    const int* __restrict__ binP, const int* __restrict__ offG,
    const int* __restrict__ blk_off1,
    const int* __restrict__ row_ptr, int* __restrict__ csr_col,
    int E, int nblk, int N) {
    __shared__ int cur[512];
    int b = blockIdx.x;
    int rbase = b << 9;
    if (rbase >= N) return;
    int t = threadIdx.x;
    for (int i = t; i < 512; i += 256) {
        int r = rbase + i;
        cur[i] = (r < N) ? row_ptr[r] : 0;
    }
    __syncthreads();
    int i0 = b * nblk;
    int bs = offG[i0] + blk_off1[i0 >> 10];
    int be = E;
    if (b + 1 < 256) {
        int i1 = (b + 1) * nblk;
        be = offG[i1] + blk_off1[i1 >> 10];
    }
    for (int e = bs + t; e < be; e += 256) {
        int pk = binP[e];
        int rl = pk >> 17;
        int c = pk & 0x1ffff;
        int p = atomicAdd(&cur[rl], 1);
        csr_col[p] = c;
    }
}

// ---------------- MFMA GEMM (layer 1: X @ W1) ------------------------------
// C[M,NCOLS](bf16) = dinv[row] * (A[M,KTOT] @ Bt^T); Bt is [NCOLS][KTOT] bf16.
// MFMA layouts (HW-verified per guide m89/m120):
//   a_frag lane l: A[m=l&15][k=(l>>4)*8+j]
//   b_frag lane l: B[k=(l>>4)*8+j][n=l&15]
//   d      lane l: D[row=(l>>4)*4+r][col=l&15]
template <int KTOT, int NCOLS, bool AF32>
__global__ __launch_bounds__(256) void gemm_mfma_kernel(
    const void* __restrict__ Aptr, const ushort* __restrict__ Bt,
    const float* __restrict__ dinv, ushort* __restrict__ Cbf, int M) {
    constexpr int KP = 128;
    constexpr int COLT = NCOLS / 16;
    __shared__ ushort Bs[NCOLS][KP + 8];
    int tid = threadIdx.x;
    int wave = tid >> 6, lane = tid & 63;
    int quad = lane >> 4, l16 = lane & 15;
    int row0 = blockIdx.x * 64;
    int rowA = row0 + wave * 16 + l16;
    int rowAc = min(rowA, M - 1);

    floatx4 acc[COLT];
#pragma unroll
    for (int t = 0; t < COLT; t++) acc[t] = (floatx4){0.f, 0.f, 0.f, 0.f};

    for (int kp = 0; kp < KTOT; kp += KP) {
        for (int u = tid; u < NCOLS * (KP / 8); u += 256) {
            int n = u / (KP / 8);
            int k8 = (u % (KP / 8)) * 8;
            *(short8*)&Bs[n][k8] = *(const short8*)(Bt + (size_t)n * KTOT + kp + k8);
        }
        __syncthreads();
#pragma unroll
        for (int kc = 0; kc < KP / 32; kc++) {
            int kk = kp + kc * 32 + quad * 8;
            short8 a;
            if (AF32) {
                const float* ap = (const float*)Aptr + (size_t)rowAc * KTOT + kk;
                float4 f0 = *(const float4*)ap;
                float4 f1 = *(const float4*)(ap + 4);
                a[0] = (short)f32_to_bf16_bits(f0.x);
                a[1] = (short)f32_to_bf16_bits(f0.y);
                a[2] = (short)f32_to_bf16_bits(f0.z);
                a[3] = (short)f32_to_bf16_bits(f0.w);
                a[4] = (short)f32_to_bf16_bits(f1.x);
                a[5] = (short)f32_to_bf16_bits(f1.y);
                a[6] = (short)f32_to_bf16_bits(f1.z);
                a[7] = (short)f32_to_bf16_bits(f1.w);
            } else {
                a = *(const short8*)((const ushort*)Aptr + (size_t)rowAc * KTOT + kk);
            }
#pragma unroll
            for (int t = 0; t < COLT; t++) {
                short8 b = *(const short8*)&Bs[t * 16 + l16][kc * 32 + quad * 8];
                acc[t] = __builtin_amdgcn_mfma_f32_16x16x32_bf16(a, b, acc[t], 0, 0, 0);
            }
        }
        __syncthreads();
    }

#pragma unroll
    for (int r = 0; r < 4; r++) {
        int row = row0 + wave * 16 + quad * 4 + r;
        if (row < M) {
            float dv = dinv[row];
#pragma unroll
            for (int t = 0; t < COLT; t++)
                Cbf[(size_t)row * NCOLS + t * 16 + l16] = f32_to_bf16_bits(dv * acc[t][r]);
        }
    }
}

// ---------------- fused SpMM(F=128) + GEMM2 --------------------------------
// Per block: 16 rows. Phase A (SpMM): H-rows = relu(dinv .* gather-sum XW1),
// kept in registers, dropped to LDS as bf16. Phase B (GEMM2): each lane loads
// its W2 b-frags (4x short8, 16 VGPR) straight from L2-hot W2t; wave wv does
// cols wv*16..+15 via 4 MFMA. H never touches global. LDS = 8.4 KB only
// (cstage + Hs) so occupancy stays high for the gather phase.
__global__ __launch_bounds__(256) void spmm_gemm2_kernel(
    const int* __restrict__ row_ptr, const int* __restrict__ cols,
    const float* __restrict__ dinv, const ushort* __restrict__ XW1,
    const ushort* __restrict__ W2t, ushort* __restrict__ HW2, int n) {
    __shared__ int cstage[SPMM_CHUNK];
    __shared__ ushort Hs[16][136];

    int tid = threadIdx.x;
    int wv = tid >> 6;
    int lane = tid & 63;
    int g = lane >> 4, lg = lane & 15;
    int r0 = blockIdx.x * 16;
    int row = r0 + wv * 4 + g;
    bool ok = row < n;
    int rc = ok ? row : (n - 1);
    int beg = row_ptr[rc];
    int end = ok ? row_ptr[rc + 1] : beg;
    int bbeg = row_ptr[r0];
    int bend = row_ptr[min(r0 + 16, n)];

    floatx2 acc2[4];
#pragma unroll
    for (int i = 0; i < 4; i++) acc2[i] = (floatx2){0.f, 0.f};

    const ushort* xb = XW1 + lg * 8;

#define ACC_DW(U, D)                                            \
    {                                                            \
        floatx2 v_;                                              \
        v_.x = bf16lo_to_f32(U);                                 \
        v_.y = bf16hi_to_f32(U);                                 \
        acc2[D] += v_;                                           \
    }
#define ACC_U4(UU)                                               \
    ACC_DW(UU.x, 0) ACC_DW(UU.y, 1) ACC_DW(UU.z, 2) ACC_DW(UU.w, 3)

    for (int cb = bbeg; cb < bend; cb += SPMM_CHUNK) {
        int ce = min(cb + SPMM_CHUNK, bend);
        __syncthreads();
        for (int i = cb + tid; i < ce; i += 256)
            cstage[i - cb] = cols[i];
        __syncthreads();
        int s = max(beg, cb), t_ = min(end, ce);
        int e = s;
        for (; e + 8 <= t_; e += 8) {
            int c0 = cstage[e - cb], c1 = cstage[e + 1 - cb];
            int c2 = cstage[e + 2 - cb], c3 = cstage[e + 3 - cb];
            int c4 = cstage[e + 4 - cb], c5 = cstage[e + 5 - cb];
            int c6 = cstage[e + 6 - cb], c7 = cstage[e + 7 - cb];
            uint4 u0 = *(const uint4*)(xb + (size_t)c0 * 128);
            uint4 u1 = *(const uint4*)(xb + (size_t)c1 * 128);
            uint4 u2 = *(const uint4*)(xb + (size_t)c2 * 128);
            uint4 u3 = *(const uint4*)(xb + (size_t)c3 * 128);
            uint4 u4 = *(const uint4*)(xb + (size_t)c4 * 128);
            uint4 u5 = *(const uint4*)(xb + (size_t)c5 * 128);
            uint4 u6 = *(const uint4*)(xb + (size_t)c6 * 128);
            uint4 u7 = *(const uint4*)(xb + (size_t)c7 * 128);
            ACC_U4(u0) ACC_U4(u1) ACC_U4(u2) ACC_U4(u3)
            ACC_U4(u4) ACC_U4(u5) ACC_U4(u6) ACC_U4(u7)
        }
        for (; e + 4 <= t_; e += 4) {
            int c0 = cstage[e - cb], c1 = cstage[e + 1 - cb];
            int c2 = cstage[e + 2 - cb], c3 = cstage[e + 3 - cb];
            uint4 u0 = *(const uint4*)(xb + (size_t)c0 * 128);
            uint4 u1 = *(const uint4*)(xb + (size_t)c1 * 128);
            uint4 u2 = *(const uint4*)(xb + (size_t)c2 * 128);
            uint4 u3 = *(const uint4*)(xb + (size_t)c3 * 128);
            ACC_U4(u0) ACC_U4(u1) ACC_U4(u2) ACC_U4(u3)
        }
        for (; e < t_; e++) {
            int c = cstage[e - cb];
            uint4 u = *(const uint4*)(xb + (size_t)c * 128);
            ACC_U4(u)
        }
    }
#undef ACC_U4
#undef ACC_DW

    // H row -> LDS (zeros for padding rows)
    {
        float dv = ok ? dinv[row] : 0.f;
        float a0 = fmaxf(dv * acc2[0].x, 0.f), a1 = fmaxf(dv * acc2[0].y, 0.f);
        float a2 = fmaxf(dv * acc2[1].x, 0.f), a3 = fmaxf(dv * acc2[1].y, 0.f);
        float a4 = fmaxf(dv * acc2[2].x, 0.f), a5 = fmaxf(dv * acc2[2].y, 0.f);
        float a6 = fmaxf(dv * acc2[3].x, 0.f), a7 = fmaxf(dv * acc2[3].y, 0.f);
        uint4 o;
        o.x = pack2bf(a0, a1);
        o.y = pack2bf(a2, a3);
        o.z = pack2bf(a4, a5);
        o.w = pack2bf(a6, a7);
        *(uint4*)&Hs[wv * 4 + g][lg * 8] = o;
    }
    __syncthreads();

    // GEMM2: wave wv computes D[0:16][wv*16 : wv*16+16]; b-frags from global
    // (W2t is 16 KB, L2-resident after the first few blocks).
    short8 bf[4];
#pragma unroll
    for (int kc = 0; kc < 4; kc++)
        bf[kc] = *(const short8*)(W2t + (wv * 16 + lg) * 128 + kc * 32 + g * 8);
    floatx4 dacc = (floatx4){0.f, 0.f, 0.f, 0.f};
#pragma unroll
    for (int kc = 0; kc < 4; kc++) {
        short8 a = *(const short8*)&Hs[lg][kc * 32 + g * 8];
        dacc = __builtin_amdgcn_mfma_f32_16x16x32_bf16(a, bf[kc], dacc, 0, 0, 0);
    }
#pragma unroll
    for (int r = 0; r < 4; r++) {
        int rowD = r0 + g * 4 + r;
        if (rowD < n)
            HW2[(size_t)rowD * 64 + wv * 16 + lg] =
                f32_to_bf16_bits(dinv[rowD] * dacc[r]);
    }
}

// ---------------- SpMM F=64 (final layer), fp32 out ------------------------
// 8 lanes/row x dwordx4 (16B = 8 features each), 8 rows/wave, 32 rows/block.
__global__ __launch_bounds__(256) void spmm_f64_kernel(
    const int* __restrict__ row_ptr, const int* __restrict__ cols,
    const float* __restrict__ dinv, const ushort* __restrict__ Xin,
    float* __restrict__ Yout, int n) {
    __shared__ int cstage[SPMM_CHUNK];
    int r0 = blockIdx.x * 32;
    int tid = threadIdx.x;
    int wv = tid >> 6;
    int lane = tid & 63;
    int h = lane >> 3, lh = lane & 7;
    int row = r0 + wv * 8 + h;
    bool ok = row < n;
    int rc = ok ? row : (n - 1);
    int beg = row_ptr[rc];
    int end = ok ? row_ptr[rc + 1] : beg;
    int bbeg = row_ptr[r0];
    int bend = row_ptr[min(r0 + 32, n)];

    floatx2 acc2[4];
#pragma unroll
    for (int i = 0; i < 4; i++) acc2[i] = (floatx2){0.f, 0.f};

    const ushort* xb = Xin + lh * 8;

#define ACC_DW(U, D)                                            \
    {                                                            \
        floatx2 v_;                                              \
        v_.x = bf16lo_to_f32(U);                                 \
        v_.y = bf16hi_to_f32(U);                                 \
        acc2[D] += v_;                                           \
    }
#define ACC_U4(UU)                                               \
    ACC_DW(UU.x, 0) ACC_DW(UU.y, 1) ACC_DW(UU.z, 2) ACC_DW(UU.w, 3)

    for (int cb = bbeg; cb < bend; cb += SPMM_CHUNK) {
        int ce = min(cb + SPMM_CHUNK, bend);
        __syncthreads();
        for (int i = cb + tid; i < ce; i += 256)
            cstage[i - cb] = cols[i];
        __syncthreads();
        int s = max(beg, cb), t_ = min(end, ce);
        int e = s;
        for (; e + 8 <= t_; e += 8) {
            int c0 = cstage[e - cb], c1 = cstage[e + 1 - cb];
            int c2 = cstage[e + 2 - cb], c3 = cstage[e + 3 - cb];
            int c4 = cstage[e + 4 - cb], c5 = cstage[e + 5 - cb];
            int c6 = cstage[e + 6 - cb], c7 = cstage[e + 7 - cb];
            uint4 u0 = *(const uint4*)(xb + (size_t)c0 * 64);
            uint4 u1 = *(const uint4*)(xb + (size_t)c1 * 64);
            uint4 u2 = *(const uint4*)(xb + (size_t)c2 * 64);
            uint4 u3 = *(const uint4*)(xb + (size_t)c3 * 64);
            uint4 u4 = *(const uint4*)(xb + (size_t)c4 * 64);
            uint4 u5 = *(const uint4*)(xb + (size_t)c5 * 64);
            uint4 u6 = *(const uint4*)(xb + (size_t)c6 * 64);
            uint4 u7 = *(const uint4*)(xb + (size_t)c7 * 64);
            ACC_U4(u0) ACC_U4(u1) ACC_U4(u2) ACC_U4(u3)
            ACC_U4(u4) ACC_U4(u5) ACC_U4(u6) ACC_U4(u7)
        }
        for (; e + 4 <= t_; e += 4) {
            int c0 = cstage[e - cb], c1 = cstage[e + 1 - cb];
            int c2 = cstage[e + 2 - cb], c3 = cstage[e + 3 - cb];
            uint4 u0 = *(const uint4*)(xb + (size_t)c0 * 64);
            uint4 u1 = *(const uint4*)(xb + (size_t)c1 * 64);
            uint4 u2 = *(const uint4*)(xb + (size_t)c2 * 64);
            uint4 u3 = *(const uint4*)(xb + (size_t)c3 * 64);
            ACC_U4(u0) ACC_U4(u1) ACC_U4(u2) ACC_U4(u3)
        }
        for (; e < t_; e++) {
            int c = cstage[e - cb];
            uint4 u = *(const uint4*)(xb + (size_t)c * 64);
            ACC_U4(u)
        }
    }
#undef ACC_U4
#undef ACC_DW

    if (ok) {
        float dv = dinv[row];
        float4 o0 = make_float4(dv * acc2[0].x, dv * acc2[0].y,
                                dv * acc2[1].x, dv * acc2[1].y);
        float4 o1 = make_float4(dv * acc2[2].x, dv * acc2[2].y,
                                dv * acc2[3].x, dv * acc2[3].y);
        float* yp = Yout + (size_t)row * 64 + lh * 8;
        *(float4*)yp = o0;
        *(float4*)(yp + 4) = o1;
    }
}

// ---------------- launch ----------------------------------------------------

extern "C" void kernel_launch(void* const* d_in, const int* in_sizes, int n_in,
                              void* d_out, int out_size, void* d_ws, size_t ws_size,
                              hipStream_t stream) {
    const float* X  = (const float*)d_in[0];
    const float* W1 = (const float*)d_in[1];
    const float* W2 = (const float*)d_in[2];
    const int* erow = (const int*)d_in[3];
    const int* ecol = (const int*)d_in[4];

    const int N = in_sizes[0] / 256;  // 100000 (< 2^17 for binP packing)
    const int E = in_sizes[3];        // 1700000
    const int G = (N + 1023) >> 10;   // row scan blocks (98 <= 256)

    const int nblk = (E + CSR_EPB - 1) / CSR_EPB;  // 208
    const int SL = 256 * nblk;                     // hist scan length
    const int GS = (SL + 1023) >> 10;              // 52 <= 256
    const int GMAX = (G > GS) ? G : GS;
    const int CAST_BLKS = (256 * 128 + 128 * 64 + 255) / 256;  // 160

    char* ws = (char*)d_ws;
    size_t off = 0;
    auto carve = [&](size_t bytes) -> char* {
        char* p = ws + off;
        off += (bytes + 255) & ~(size_t)255;
        return p;
    };
    int*    deg       = (int*)   carve((size_t)N * 4);
    float*  dinv      = (float*) carve((size_t)N * 4);
    int*    row_ptr   = (int*)   carve((size_t)(N + 1) * 4);
    int*    blk_total = (int*)   carve((size_t)GMAX * 4);
    int*    blk_off1  = (int*)   carve((size_t)(GMAX + 1) * 4);
    int*    blk_off2  = (int*)   carve((size_t)(GMAX + 1) * 4);
    int*    offG      = (int*)   carve((size_t)(SL + 1) * 4);
    // union: binP (E*4) dead before GEMM1 writes XW1 (N*128*2).
    size_t binP_bytes = (size_t)E * 4;
    size_t xw1_bytes  = (size_t)N * 128 * 2;
    char*  uni        = carve(binP_bytes > xw1_bytes ? binP_bytes : xw1_bytes);
    int*    binP      = (int*)uni;
    ushort* XW1       = (ushort*)uni;
    int*    csr_col   = (int*)   carve((size_t)E * 4);
    ushort* W1t       = (ushort*)carve((size_t)256 * 128 * 2);  // [128][256]
    ushort* W2t       = (ushort*)carve((size_t)128 * 64 * 2);   // [64][128]
    ushort* HW2       = (ushort*)carve((size_t)N * 64 * 2);

    // --- CSR build: row-bucket counting sort (+ weight cast piggy-backed) ---
    edge_hist_cast_kernel<<<nblk + CAST_BLKS, 256, 0, stream>>>(
        erow, offG, E, nblk, W1, W2, W1t, W2t);
    scan_phase1_kernel<<<GS, 256, 0, stream>>>(offG, offG, blk_total, SL);
    scan_phase2_kernel<<<1, 256, 0, stream>>>(blk_total, blk_off1, GS);
    // (chain-1 phase3 folded into consumers via blk_off1)
    edge_bin_kernel<<<nblk, 256, 0, stream>>>(erow, ecol, offG, blk_off1, binP, E, nblk);

    deg_dinv_from_bin_kernel<<<256, 256, 0, stream>>>(binP, offG, blk_off1, deg, dinv, E, nblk, N);
    scan_phase1_kernel<<<G, 256, 0, stream>>>(deg, row_ptr, blk_total, N);
    scan_phase2_kernel<<<1, 256, 0, stream>>>(blk_total, blk_off2, G);
    scan_phase3_kernel<<<(N + 255) / 256, 256, 0, stream>>>(row_ptr, blk_off2, N, G);

    edge_scatter_kernel<<<256, 256, 0, stream>>>(binP, offG, blk_off1, row_ptr, csr_col, E, nblk, N);

    // GEMM1: XW1(bf16) = dinv .* (X @ W1)   (overwrites binP — dead)
    gemm_mfma_kernel<256, 128, true><<<(N + 63) / 64, 256, 0, stream>>>(
        (const void*)X, W1t, dinv, XW1, N);

    // SpMM1 + GEMM2 fused: HW2(bf16) = dinv .* (relu(dinv .* gather XW1) @ W2)
    spmm_gemm2_kernel<<<(N + 15) / 16, 256, 0, stream>>>(
        row_ptr, csr_col, dinv, XW1, W2t, HW2, N);

    // SpMM2: out(fp32) = dinv .* sum gather HW2
    spmm_f64_kernel<<<(N + 31) / 32, 256, 0, stream>>>(row_ptr, csr_col, dinv, HW2, (float*)d_out, N);
}